// Round 6
// baseline (93.450 us; speedup 1.0000x reference)
//
#include <hip/hip_runtime.h>
#include <hip/hip_bf16.h>

typedef __bf16 bf16_t;
typedef bf16_t bf16x8 __attribute__((ext_vector_type(8)));
typedef bf16_t bf16x4 __attribute__((ext_vector_type(4)));
typedef float  floatx4 __attribute__((ext_vector_type(4)));

#define NROWS 65536
#define NCENT 512
#define NDIM  128
#define TROWS 64
#define TPB   4
#define NBLK  (NROWS / (TROWS * TPB))   // 256 blocks x 1024 thr = 1 block/CU

// ws: [0,131072) mu bf16 frag-major  addr = (col>>4)*2048 + kk*512 + quad*128 + (col&15)*8
//     [131072,133120) h2 = 0.5*|mu_bf16|^2 float[512]

__global__ __launch_bounds__(256)
void mu_pack_kernel(const float* __restrict__ mu, bf16_t* __restrict__ ws_mu,
                    float* __restrict__ ws_h2, float* __restrict__ out)
{
    const int tid = threadIdx.x;
    if (blockIdx.x == 0 && tid == 0) *out = 0.f;   // replaces the memset dispatch
    const int col_local = tid >> 5;     // 8 cols per block
    const int j = tid & 31;             // 32 threads per col, 4 floats each
    const int col = blockIdx.x * 8 + col_local;
    const float4 v = *(const float4*)(mu + col * NDIM + j * 4);
    bf16x4 pk = {(bf16_t)v.x, (bf16_t)v.y, (bf16_t)v.z, (bf16_t)v.w};
    const int k0 = j * 4;
    const int kk = k0 >> 5, quad = (k0 >> 3) & 3, e0 = k0 & 7;
    const int addr = (col >> 4) * 2048 + kk * 512 + quad * 128 + (col & 15) * 8 + e0;
    *(bf16x4*)(ws_mu + addr) = pk;
    float f0 = (float)pk[0], f1 = (float)pk[1], f2 = (float)pk[2], f3 = (float)pk[3];
    float s = f0 * f0 + f1 * f1 + f2 * f2 + f3 * f3;
    s += __shfl_xor(s, 1);  s += __shfl_xor(s, 2);  s += __shfl_xor(s, 4);
    s += __shfl_xor(s, 8);  s += __shfl_xor(s, 16);
    if (j == 0) ws_h2[col] = 0.5f * s;
}

// main: R5 body restructured to ONE barrier per tile.
//  - ds_write of tile t+1 moved to phase start (zt[cur^1] idle since barrier t-1)
//  - rmx/z2s double-buffered by tile parity (epilogue t overlaps compute t+1)
//  - t+2 prefetch issued right after staging regs are freed
__global__ __launch_bounds__(1024, 4)
void kmeans_main(const float* __restrict__ z, const bf16_t* __restrict__ wmu,
                 const float* __restrict__ wh2, float* __restrict__ out)
{
    __shared__ bf16_t zt[2][TROWS * NDIM];   // 2 x 16 KB
    __shared__ float  z2s[2][TROWS];         // 512 B
    __shared__ float  rmx[2][16][TROWS];     // 8 KB   -> 40.7 KB total

    const int tid  = threadIdx.x;
    const int lane = tid & 63;
    const int w    = tid >> 6;        // wave 0..15; owns cols [w*32, w*32+32)
    const int quad = lane >> 4;
    const int l16  = lane & 15;

    // staging map: thread (s,kk,q,r16) <-> 32B global rect / 16B LDS frag chunk
    const int c_s   = tid >> 8;
    const int c_kk  = (tid >> 6) & 3;
    const int c_q   = (tid >> 4) & 3;
    const int c_r16 = tid & 15;
    const int g_off = (c_s * 16 + c_r16) * NDIM + c_kk * 32 + c_q * 8;   // float idx
    const int l_off = c_s * 2048 + c_kk * 512 + c_q * 128 + c_r16 * 8;   // bf16 idx

    const size_t zb0 = (size_t)blockIdx.x * TPB * TROWS * NDIM;

    // ---- prologue: tile-0 loads -> bfr loads -> tile-0 write -> tile-1 loads ----
    float4 a0 = *(const float4*)(z + zb0 + g_off);
    float4 a1 = *(const float4*)(z + zb0 + g_off + 4);

    bf16x8 bfr[2][4];
    float  h2r[2];
#pragma unroll
    for (int g = 0; g < 2; ++g) {
        const int j = w * 2 + g;   // col group; col = j*16 + l16
#pragma unroll
        for (int kk = 0; kk < 4; ++kk)
            bfr[g][kk] = *(const bf16x8*)(wmu + j * 2048 + kk * 512 + quad * 128 + l16 * 8);
        h2r[g] = wh2[j * 16 + l16];
    }

    {
        bf16x8 pk = {(bf16_t)a0.x, (bf16_t)a0.y, (bf16_t)a0.z, (bf16_t)a0.w,
                     (bf16_t)a1.x, (bf16_t)a1.y, (bf16_t)a1.z, (bf16_t)a1.w};
        *(bf16x8*)&zt[0][l_off] = pk;
    }
    {
        const float* zp = z + zb0 + (size_t)TROWS * NDIM + g_off;   // tile 1
        a0 = *(const float4*)(zp);
        a1 = *(const float4*)(zp + 4);
    }
    __syncthreads();   // tile 0 visible (drains tile-1 loads too; prologue-only cost)

    float fsum = 0.f;

    for (int t = 0; t < TPB; ++t) {
        const int cur = t & 1;

        // ---- stage tile t+1 into the idle buffer (free since barrier t-1) ----
        if (t + 1 < TPB) {
            bf16x8 pk = {(bf16_t)a0.x, (bf16_t)a0.y, (bf16_t)a0.z, (bf16_t)a0.w,
                         (bf16_t)a1.x, (bf16_t)a1.y, (bf16_t)a1.z, (bf16_t)a1.w};
            *(bf16x8*)&zt[cur ^ 1][l_off] = pk;
        }
        // ---- staging regs free: issue t+2 loads; whole compute phase of cover ----
        if (t + 2 < TPB) {
            const float* zp = z + zb0 + (size_t)(t + 2) * TROWS * NDIM + g_off;
            a0 = *(const float4*)(zp);
            a1 = *(const float4*)(zp + 4);
        }

        // ---- compute: 4 strips x (2 colgroups x 4 MFMA) from zt[cur] ----
#pragma unroll
        for (int s = 0; s < 4; ++s) {
            bf16x8 afr[4];
#pragma unroll
            for (int kk = 0; kk < 4; ++kk)
                afr[kk] = *(const bf16x8*)&zt[cur][s * 2048 + kk * 512 + quad * 128 + l16 * 8];

            float vm[4] = {-3.0e38f, -3.0e38f, -3.0e38f, -3.0e38f};
#pragma unroll
            for (int g = 0; g < 2; ++g) {
                floatx4 acc = (floatx4){0.f, 0.f, 0.f, 0.f};
#pragma unroll
                for (int kk = 0; kk < 4; ++kk)
                    acc = __builtin_amdgcn_mfma_f32_16x16x32_bf16(afr[kk], bfr[g][kk], acc, 0, 0, 0);
#pragma unroll
                for (int r = 0; r < 4; ++r)
                    vm[r] = fmaxf(vm[r], acc[r] - h2r[g]);   // deferred-sqrt: max(dot - m2/2)
            }

            if (w == s) {   // z2 of rounded z for strip s (uniform branch, 1 wave)
                float ss = 0.f;
#pragma unroll
                for (int kk = 0; kk < 4; ++kk)
#pragma unroll
                    for (int e = 0; e < 8; ++e) { float f = (float)afr[kk][e]; ss = fmaf(f, f, ss); }
                ss += __shfl_xor(ss, 16);
                ss += __shfl_xor(ss, 32);
                if (lane < 16) z2s[cur][s * 16 + lane] = ss;
            }

#pragma unroll
            for (int r = 0; r < 4; ++r) {                    // max over this wave's 16 cols
                float v = vm[r];
                v = fmaxf(v, __shfl_xor(v, 1));
                v = fmaxf(v, __shfl_xor(v, 2));
                v = fmaxf(v, __shfl_xor(v, 4));
                v = fmaxf(v, __shfl_xor(v, 8));
                if (l16 == 0) rmx[cur][w][s * 16 + quad * 4 + r] = v;
            }
        }
        __syncthreads();   // SINGLE barrier: zt[cur^1] staged + rmx/z2s[cur] visible

        // ---- epilogue for tile t; overlaps next tile's compute (parity-buffered) ----
        if (tid < TROWS) {
            float m = rmx[cur][0][tid];
#pragma unroll
            for (int jj = 1; jj < 16; ++jj) m = fmaxf(m, rmx[cur][jj][tid]);
            float d2 = z2s[cur][tid] - 2.0f * m;
            fsum += sqrtf(fmaxf(d2, 0.f));
        }
    }

    // ---- wave 0 holds all row sums; reduce + one atomic per block ----
    if (w == 0) {
        float v = fsum;
#pragma unroll
        for (int off = 32; off; off >>= 1) v += __shfl_down(v, off);
        if (tid == 0) atomicAdd(out, v * (1.0f / 65536.0f));
    }
}

extern "C" void kernel_launch(void* const* d_in, const int* in_sizes, int n_in,
                              void* d_out, int out_size, void* d_ws, size_t ws_size,
                              hipStream_t stream) {
    const float* z  = (const float*)d_in[0];
    const float* mu = (const float*)d_in[1];
    float* out = (float*)d_out;
    bf16_t* ws_mu = (bf16_t*)d_ws;
    float*  ws_h2 = (float*)((char*)d_ws + 131072);
    mu_pack_kernel<<<dim3(64),   dim3(256),  0, stream>>>(mu, ws_mu, ws_h2, out);
    kmeans_main   <<<dim3(NBLK), dim3(1024), 0, stream>>>(z, ws_mu, ws_h2, out);
}

// Round 7
// 87.993 us; speedup vs baseline: 1.0620x; 1.0620x over previous
//
#include <hip/hip_runtime.h>
#include <hip/hip_bf16.h>

typedef __bf16 bf16_t;
typedef bf16_t bf16x8 __attribute__((ext_vector_type(8)));
typedef bf16_t bf16x4 __attribute__((ext_vector_type(4)));
typedef float  floatx4 __attribute__((ext_vector_type(4)));

#define NROWS 65536
#define NCENT 512
#define NDIM  128
#define NBLK  256
#define TROWS 64
#define NTILE (NROWS / (NBLK * TROWS))   // 4
#define ZPITCH 136   // 128 + 8 bf16 pad

// d_ws: [0,131072) mu bf16 frag-major; [131072,133120) h2 = 0.5*|mu|^2 float[512]
// frag-major (col,k): addr = j*2048 + kk*512 + quad*128 + l16*8 + e
//   col = j*16+l16, k = kk*32+quad*8+e  -> B-frag ds_read_b128 is 1KB contiguous/wave

__device__ __forceinline__ void gload_lds16(const bf16_t* g, bf16_t* l) {
    __builtin_amdgcn_global_load_lds(
        (const __attribute__((address_space(1))) unsigned int*)g,
        (__attribute__((address_space(3))) unsigned int*)l,
        16, 0, 0);
}

__global__ __launch_bounds__(256)
void mu_pack_kernel(const float* __restrict__ mu, bf16_t* __restrict__ ws_mu,
                    float* __restrict__ ws_h2, float* __restrict__ out)
{
    const int tid = threadIdx.x;
    if (blockIdx.x == 0 && tid == 0) *out = 0.f;   // folds the memset dispatch away
    const int col_local = tid >> 5;     // 8 cols per block
    const int j = tid & 31;             // 32 threads per col, 4 floats each
    const int col = blockIdx.x * 8 + col_local;
    const float4 v = *(const float4*)(mu + col * NDIM + j * 4);
    bf16x4 pk = {(bf16_t)v.x, (bf16_t)v.y, (bf16_t)v.z, (bf16_t)v.w};
    const int k0 = j * 4;
    const int kk = k0 >> 5, quad = (k0 >> 3) & 3, e0 = k0 & 7;
    const int c = col >> 6, g = (col >> 4) & 3, c16 = col & 15;
    const int addr = c * 8192 + g * 2048 + kk * 512 + quad * 128 + c16 * 8 + e0;
    *(bf16x4*)(ws_mu + addr) = pk;
    float f0 = (float)pk[0], f1 = (float)pk[1], f2 = (float)pk[2], f3 = (float)pk[3];
    float s = f0 * f0 + f1 * f1 + f2 * f2 + f3 * f3;
    s += __shfl_xor(s, 1);  s += __shfl_xor(s, 2);  s += __shfl_xor(s, 4);
    s += __shfl_xor(s, 8);  s += __shfl_xor(s, 16);
    if (j == 0) ws_h2[col] = 0.5f * s;
}

__global__ __launch_bounds__(512, 2)
void kmeans_main(const float* __restrict__ z, const bf16_t* __restrict__ ws_mu,
                 const float* __restrict__ ws_h2, float* __restrict__ out)
{
    __shared__ bf16_t muf[NCENT * NDIM];       // 131072 B, frag-major, resident all kernel
    __shared__ bf16_t ztile[TROWS * ZPITCH];   // 17408 B
    __shared__ float h2s[NCENT];               // 2048 B
    __shared__ float z2s[TROWS];               // 256 B
    __shared__ float rmx[TROWS][2];            // 512 B    -> ~151 KB total, 1 block/CU

    const int tid  = threadIdx.x;
    const int lane = tid & 63;
    const int w    = tid >> 6;
    const int quad = lane >> 4;
    const int l16  = lane & 15;
    const int s    = w >> 1;     // row strip 0..3 (16 rows each)
    const int h    = w & 1;      // column half: groups h*16 .. h*16+15

    // ---- prefetch z tile 0 into VGPRs (coalesced: 32B per thread) ----
    float4 pf[4];
    {
        const float4* zsrc = (const float4*)(z + (size_t)blockIdx.x * TROWS * NDIM);
#pragma unroll
        for (int i = 0; i < 2; ++i) {
            int q8 = i * 512 + tid;
            pf[2*i]     = zsrc[q8 * 2];
            pf[2*i + 1] = zsrc[q8 * 2 + 1];
        }
    }

    // ---- stage ALL of mu (128 KB bf16) direct to LDS, once ----
#pragma unroll
    for (int i = 0; i < 16; ++i) {
        int idx = i * 512 + tid;                 // 16B units
        gload_lds16(ws_mu + idx * 8, &muf[idx * 8]);
    }
    h2s[tid] = ws_h2[tid];

    float fsum = 0.f;

    for (int t = 0; t < NTILE; ++t) {
        // ---- stage ztile (cvt fp32->bf16) + per-row z2 from rounded values ----
#pragma unroll
        for (int i = 0; i < 2; ++i) {
            int q8 = i * 512 + tid;              // 8-float unit; 16 units per row
            float4 va = pf[2*i], vb = pf[2*i + 1];
            int r = q8 >> 4, c8 = (q8 & 15) << 3;
            bf16x8 pk = {(bf16_t)va.x, (bf16_t)va.y, (bf16_t)va.z, (bf16_t)va.w,
                         (bf16_t)vb.x, (bf16_t)vb.y, (bf16_t)vb.z, (bf16_t)vb.w};
            *(bf16x8*)&ztile[r * ZPITCH + c8] = pk;
            float ss = 0.f;
#pragma unroll
            for (int e = 0; e < 8; ++e) { float f = (float)pk[e]; ss = fmaf(f, f, ss); }
            ss += __shfl_xor(ss, 1); ss += __shfl_xor(ss, 2);
            ss += __shfl_xor(ss, 4); ss += __shfl_xor(ss, 8);
            if (l16 == 0) z2s[r] = ss;           // 16 lanes per row, lane group-leader writes
        }
        __syncthreads();   // B1: ztile+z2s visible; also drains mu gload (t==0)

        // ---- issue prefetch of tile t+1 (hidden under the MFMA phase) ----
        if (t + 1 < NTILE) {
            const float4* zsrc = (const float4*)(z + ((size_t)(t + 1) * NBLK + blockIdx.x) * TROWS * NDIM);
#pragma unroll
            for (int i = 0; i < 2; ++i) {
                int q8 = i * 512 + tid;
                pf[2*i]     = zsrc[q8 * 2];
                pf[2*i + 1] = zsrc[q8 * 2 + 1];
            }
        }

        // ---- A fragments for this wave's 16-row strip ----
        bf16x8 afr[4];
#pragma unroll
        for (int kk = 0; kk < 4; ++kk)
            afr[kk] = *(const bf16x8*)&ztile[(s * 16 + l16) * ZPITCH + kk * 32 + quad * 8];

        float tm[4] = {-3.0e38f, -3.0e38f, -3.0e38f, -3.0e38f};
#pragma unroll
        for (int j2 = 0; j2 < 16; ++j2) {
            const int j = h * 16 + j2;
            bf16x8 bfr[4];
#pragma unroll
            for (int kk = 0; kk < 4; ++kk)
                bfr[kk] = *(const bf16x8*)&muf[((j * 4 + kk) * 4 + quad) * 128 + l16 * 8];
            floatx4 acc = (floatx4){0.f, 0.f, 0.f, 0.f};
#pragma unroll
            for (int kk = 0; kk < 4; ++kk)
                acc = __builtin_amdgcn_mfma_f32_16x16x32_bf16(afr[kk], bfr[kk], acc, 0, 0, 0);
            float h2v = h2s[j * 16 + l16];
#pragma unroll
            for (int r = 0; r < 4; ++r)
                tm[r] = fmaxf(tm[r], acc[r] - h2v);   // deferred-sqrt: track max(dot - m2/2)
        }

        // ---- per-row max over this wave's 16 cols; publish per column-half ----
#pragma unroll
        for (int r = 0; r < 4; ++r) {
            float v = tm[r];
            v = fmaxf(v, __shfl_xor(v, 1));
            v = fmaxf(v, __shfl_xor(v, 2));
            v = fmaxf(v, __shfl_xor(v, 4));
            v = fmaxf(v, __shfl_xor(v, 8));
            if (l16 == 0) rmx[s * 16 + quad * 4 + r][h] = v;
        }
        __syncthreads();   // B2: rmx visible

        if (tid < TROWS) {
            float m  = fmaxf(rmx[tid][0], rmx[tid][1]);
            float d2 = z2s[tid] - 2.0f * m;
            fsum += sqrtf(fmaxf(d2, 0.f));    // one sqrt per row
        }
        __syncthreads();   // B3: protect rmx/z2s/ztile for next tile
    }

    // ---- wave-0 holds all row sums; reduce + one atomic per block ----
    if (w == 0) {
        float v = fsum;
#pragma unroll
        for (int off = 32; off; off >>= 1) v += __shfl_down(v, off);
        if (tid == 0) atomicAdd(out, v * (1.0f / 65536.0f));
    }
}

extern "C" void kernel_launch(void* const* d_in, const int* in_sizes, int n_in,
                              void* d_out, int out_size, void* d_ws, size_t ws_size,
                              hipStream_t stream) {
    const float* z  = (const float*)d_in[0];
    const float* mu = (const float*)d_in[1];
    float* out = (float*)d_out;
    bf16_t* ws_mu = (bf16_t*)d_ws;
    float* ws_h2 = (float*)((char*)d_ws + 131072);
    mu_pack_kernel<<<dim3(64), dim3(256), 0, stream>>>(mu, ws_mu, ws_h2, out);
    kmeans_main<<<dim3(NBLK), dim3(512), 0, stream>>>(z, ws_mu, ws_h2, out);
}

// Round 8
// 83.544 us; speedup vs baseline: 1.1186x; 1.0533x over previous
//
#include <hip/hip_runtime.h>
#include <hip/hip_bf16.h>

typedef __bf16 bf16_t;
typedef bf16_t bf16x8 __attribute__((ext_vector_type(8)));
typedef bf16_t bf16x4 __attribute__((ext_vector_type(4)));
typedef float  floatx16 __attribute__((ext_vector_type(16)));

#define NROWS 65536
#define NCENT 512
#define NDIM  128
#define NBLK  256
#define TROWS 64
#define NTILE (NROWS / (NBLK * TROWS))   // 4
#define ZPITCH 136   // 128 + 8 bf16 pad (keeps 16B alignment; row stride 272B)

// d_ws: [0,131072) mu bf16 frag-major; [131072,133120) h2 = 0.5*|mu|^2 float[512]
// storage (col,k): addr = (col>>4)*2048 + (k>>5)*512 + ((k>>3)&3)*128 + (col&15)*8 + (k&7)
// Read for 32x32x16 A-operand (col = G*32 + (lane&31), k = kc*16 + (lane>>5)*8):
//   addr = G*4096 + ((lane>>4)&1)*2048 + (lane>>5)*128 + (lane&15)*8 + kc*256
//   -> each quarter-wave reads 256B contiguous: conflict-free.

__device__ __forceinline__ void gload_lds16(const bf16_t* g, bf16_t* l) {
    __builtin_amdgcn_global_load_lds(
        (const __attribute__((address_space(1))) unsigned int*)g,
        (__attribute__((address_space(3))) unsigned int*)l,
        16, 0, 0);
}

__global__ __launch_bounds__(256)
void mu_pack_kernel(const float* __restrict__ mu, bf16_t* __restrict__ ws_mu,
                    float* __restrict__ ws_h2, float* __restrict__ out)
{
    const int tid = threadIdx.x;
    if (blockIdx.x == 0 && tid == 0) *out = 0.f;   // folds the memset dispatch away
    const int col_local = tid >> 5;     // 8 cols per block
    const int j = tid & 31;             // 32 threads per col, 4 floats each
    const int col = blockIdx.x * 8 + col_local;
    const float4 v = *(const float4*)(mu + col * NDIM + j * 4);
    bf16x4 pk = {(bf16_t)v.x, (bf16_t)v.y, (bf16_t)v.z, (bf16_t)v.w};
    const int k0 = j * 4;
    const int kk = k0 >> 5, quad = (k0 >> 3) & 3, e0 = k0 & 7;
    const int c = col >> 6, g = (col >> 4) & 3, c16 = col & 15;
    const int addr = c * 8192 + g * 2048 + kk * 512 + quad * 128 + c16 * 8 + e0;
    *(bf16x4*)(ws_mu + addr) = pk;
    float f0 = (float)pk[0], f1 = (float)pk[1], f2 = (float)pk[2], f3 = (float)pk[3];
    float s = f0 * f0 + f1 * f1 + f2 * f2 + f3 * f3;
    s += __shfl_xor(s, 1);  s += __shfl_xor(s, 2);  s += __shfl_xor(s, 4);
    s += __shfl_xor(s, 8);  s += __shfl_xor(s, 16);
    if (j == 0) ws_h2[col] = 0.5f * s;
}

__global__ __launch_bounds__(512, 2)
void kmeans_main(const float* __restrict__ z, const bf16_t* __restrict__ ws_mu,
                 const float* __restrict__ ws_h2, float* __restrict__ out)
{
    __shared__ bf16_t muf[NCENT * NDIM];       // 131072 B, frag-major, resident all kernel
    __shared__ bf16_t ztile[TROWS * ZPITCH];   // 17408 B
    __shared__ float h2s[NCENT];               // 2048 B
    __shared__ float z2s[TROWS];               // 256 B
    __shared__ float rmx[4][TROWS];            // 1024 B   -> ~151 KB, 1 block/CU

    const int tid  = threadIdx.x;
    const int lane = tid & 63;
    const int w    = tid >> 6;
    const int l16  = lane & 15;
    const int l32  = lane & 31;
    const int hk   = lane >> 5;      // K-half within a 16-k chunk
    const int S    = w >> 2;         // row strip 0..1 (32 rows each)
    const int wg   = w & 3;          // this wave covers col groups wg*4 .. wg*4+3

    // mu A-operand per-lane base (see layout note above)
    const int mubase_lane = ((lane >> 4) & 1) * 2048 + hk * 128 + l16 * 8;
    const int zrow = S * 32 + l32;   // z-row this lane owns as B-operand / D-col

    // ---- prefetch z tile 0 into VGPRs (coalesced: 32B per thread) ----
    float4 pf[4];
    {
        const float4* zsrc = (const float4*)(z + (size_t)blockIdx.x * TROWS * NDIM);
#pragma unroll
        for (int i = 0; i < 2; ++i) {
            int q8 = i * 512 + tid;
            pf[2*i]     = zsrc[q8 * 2];
            pf[2*i + 1] = zsrc[q8 * 2 + 1];
        }
    }

    // ---- stage ALL of mu (128 KB bf16) direct to LDS, once ----
#pragma unroll
    for (int i = 0; i < 16; ++i) {
        int idx = i * 512 + tid;                 // 16B units
        gload_lds16(ws_mu + idx * 8, &muf[idx * 8]);
    }
    h2s[tid] = ws_h2[tid];

    float fsum = 0.f;

    for (int t = 0; t < NTILE; ++t) {
        // ---- stage ztile (cvt fp32->bf16) + per-row z2 from rounded values ----
#pragma unroll
        for (int i = 0; i < 2; ++i) {
            int q8 = i * 512 + tid;              // 8-float unit; 16 units per row
            float4 va = pf[2*i], vb = pf[2*i + 1];
            int r = q8 >> 4, c8 = (q8 & 15) << 3;
            bf16x8 pk = {(bf16_t)va.x, (bf16_t)va.y, (bf16_t)va.z, (bf16_t)va.w,
                         (bf16_t)vb.x, (bf16_t)vb.y, (bf16_t)vb.z, (bf16_t)vb.w};
            *(bf16x8*)&ztile[r * ZPITCH + c8] = pk;
            float ss = 0.f;
#pragma unroll
            for (int e = 0; e < 8; ++e) { float f = (float)pk[e]; ss = fmaf(f, f, ss); }
            ss += __shfl_xor(ss, 1); ss += __shfl_xor(ss, 2);
            ss += __shfl_xor(ss, 4); ss += __shfl_xor(ss, 8);
            if (l16 == 0) z2s[r] = ss;           // 16 lanes per row, group-leader writes
        }
        __syncthreads();   // B1: ztile+z2s visible; also drains mu gload (t==0)

        // ---- issue prefetch of tile t+1 (hidden under the MFMA phase) ----
        if (t + 1 < NTILE) {
            const float4* zsrc = (const float4*)(z + ((size_t)(t + 1) * NBLK + blockIdx.x) * TROWS * NDIM);
#pragma unroll
            for (int i = 0; i < 2; ++i) {
                int q8 = i * 512 + tid;
                pf[2*i]     = zsrc[q8 * 2];
                pf[2*i + 1] = zsrc[q8 * 2 + 1];
            }
        }

        // ---- z fragments (B-operand) for this wave's 32-row strip; held across groups ----
        bf16x8 zfr[8];
#pragma unroll
        for (int kc = 0; kc < 8; ++kc)
            zfr[kc] = *(const bf16x8*)&ztile[zrow * ZPITCH + kc * 16 + hk * 8];

        float vmx = -3.0e38f;   // running max(dot - h2) over this wave's 128 cols, row=zrow
#pragma unroll
        for (int g = 0; g < 4; ++g) {
            const int G = wg * 4 + g;
            // acc init = -h2 (C-in): col(reg) = G*32 + (reg&3) + 8*(reg>>2) + 4*hk
            floatx16 acc;
#pragma unroll
            for (int q = 0; q < 4; ++q) {
                const float4 hv = *(const float4*)&h2s[G * 32 + q * 8 + hk * 4];
                acc[q*4+0] = -hv.x; acc[q*4+1] = -hv.y;
                acc[q*4+2] = -hv.z; acc[q*4+3] = -hv.w;
            }
            const int mb = G * 4096 + mubase_lane;
#pragma unroll
            for (int kc = 0; kc < 8; ++kc) {
                const bf16x8 mfr = *(const bf16x8*)&muf[mb + kc * 256];
                // swapped operands: D[m=mu-col][n=z-row]; lane holds 16 mu-cols of one z-row
                acc = __builtin_amdgcn_mfma_f32_32x32x16_bf16(mfr, zfr[kc], acc, 0, 0, 0);
            }
#pragma unroll
            for (int r = 0; r < 16; ++r) vmx = fmaxf(vmx, acc[r]);   // in-register col max
        }
        // pair (lane, lane^32) covers complementary col subsets of the same row
        vmx = fmaxf(vmx, __shfl_xor(vmx, 32));
        if (lane < 32) rmx[wg][zrow] = vmx;
        __syncthreads();   // B2: rmx visible

        if (tid < TROWS) {
            float m  = fmaxf(fmaxf(rmx[0][tid], rmx[1][tid]),
                             fmaxf(rmx[2][tid], rmx[3][tid]));
            float d2 = z2s[tid] - 2.0f * m;
            fsum += sqrtf(fmaxf(d2, 0.f));    // one sqrt per row
        }
        __syncthreads();   // B3: protect rmx/z2s/ztile for next tile
    }

    // ---- wave-0 holds all row sums; reduce + one atomic per block ----
    if (w == 0) {
        float v = fsum;
#pragma unroll
        for (int off = 32; off; off >>= 1) v += __shfl_down(v, off);
        if (tid == 0) atomicAdd(out, v * (1.0f / 65536.0f));
    }
}

extern "C" void kernel_launch(void* const* d_in, const int* in_sizes, int n_in,
                              void* d_out, int out_size, void* d_ws, size_t ws_size,
                              hipStream_t stream) {
    const float* z  = (const float*)d_in[0];
    const float* mu = (const float*)d_in[1];
    float* out = (float*)d_out;
    bf16_t* ws_mu = (bf16_t*)d_ws;
    float* ws_h2 = (float*)((char*)d_ws + 131072);
    mu_pack_kernel<<<dim3(64), dim3(256), 0, stream>>>(mu, ws_mu, ws_h2, out);
    kmeans_main<<<dim3(NBLK), dim3(512), 0, stream>>>(z, ws_mu, ws_h2, out);
}